// Round 2
// baseline (9217.319 us; speedup 1.0000x reference)
//
#include <hip/hip_runtime.h>
#include <math.h>

#define NN 50000
#define NE 1600000
#define FIN 128
#define EDIM 16
#define DD1 64
#define HH1 2
#define DD2 32
#define NG 64
#define NCLS 2

// ---------------- node transform: out[n, OUT] = X[n, IN] @ W + b ----------------
template<int IN, int OUT>
__global__ __launch_bounds__(256) void transform_k(const float* __restrict__ X,
    const float* __restrict__ W, const float* __restrict__ b,
    float* __restrict__ out, int n) {
  constexpr int NPB = 32;            // nodes per block
  constexpr int TPN = 256 / NPB;     // 8 threads per node
  constexpr int CPT = OUT / TPN;     // cols per thread
  __shared__ float sW[IN * OUT];
  __shared__ float sX[NPB * IN];
  int t = threadIdx.x;
  int nodeBase = blockIdx.x * NPB;
  for (int i = t; i < IN * OUT; i += 256) sW[i] = W[i];
  constexpr int XE = NPB * IN / 4;
  const float4* X4 = (const float4*)X;
  float4* sX4 = (float4*)sX;
  for (int i = t; i < XE; i += 256) {
    int node = nodeBase + i / (IN / 4);
    sX4[i] = (node < n) ? X4[(size_t)node * (IN / 4) + i % (IN / 4)]
                        : make_float4(0.f, 0.f, 0.f, 0.f);
  }
  __syncthreads();
  int ln = t / TPN;
  int cb = (t % TPN) * CPT;
  int node = nodeBase + ln;
  float acc[CPT];
#pragma unroll
  for (int j = 0; j < CPT; j++) acc[j] = b[cb + j];
  const float* xs = &sX[ln * IN];
  for (int k = 0; k < IN; k++) {
    float xv = xs[k];
#pragma unroll
    for (int j = 0; j < CPT; j++) acc[j] += xv * sW[k * OUT + cb + j];
  }
  if (node < n) {
#pragma unroll
    for (int j = 0; j < CPT; j++) out[(size_t)node * OUT + cb + j] = acc[j];
  }
}

// ---------------- edge score pass: ex[e,h], denom[dst,h] ----------------
template<int D, int H>
__global__ __launch_bounds__(256) void edge_score_k(
    const int* __restrict__ ei, const float* __restrict__ eattr,
    const float* __restrict__ xl, const float* __restrict__ xr,
    const float* __restrict__ We, const float* __restrict__ att,
    float* __restrict__ exbuf, float* __restrict__ denom) {
  constexpr int C = D / H;
  __shared__ float sWe[EDIM * D];
  __shared__ float sAtt[D];
  int t = threadIdx.x;
  for (int i = t; i < EDIM * D; i += 256) sWe[i] = We[i];
  for (int i = t; i < D; i += 256) sAtt[i] = att[i];
  __syncthreads();
  int e = blockIdx.x * 256 + t;
  if (e >= NE) return;
  int src = ei[e], dst = ei[NE + e];
  float ea[EDIM];
  const float4* ea4 = (const float4*)(eattr + (size_t)e * EDIM);
#pragma unroll
  for (int q = 0; q < EDIM / 4; q++) {
    float4 v = ea4[q];
    ea[4 * q] = v.x; ea[4 * q + 1] = v.y; ea[4 * q + 2] = v.z; ea[4 * q + 3] = v.w;
  }
  const float4* xls = (const float4*)(xl + (size_t)src * D);
  const float4* xrd = (const float4*)(xr + (size_t)dst * D);
  float sc[H];
#pragma unroll
  for (int h = 0; h < H; h++) sc[h] = 0.f;
#pragma unroll
  for (int q = 0; q < D / 4; q++) {
    float4 a = xls[q], r = xrd[q];
    float av[4] = {a.x, a.y, a.z, a.w};
    float rv[4] = {r.x, r.y, r.z, r.w};
#pragma unroll
    for (int j = 0; j < 4; j++) {
      int hc = 4 * q + j;
      float ef = 0.f;
#pragma unroll
      for (int k = 0; k < EDIM; k++) ef += ea[k] * sWe[k * D + hc];
      float m = av[j] + rv[j] + ef;
      m = m > 0.f ? m : 0.2f * m;
      sc[hc / C] += m * sAtt[hc];
    }
  }
#pragma unroll
  for (int h = 0; h < H; h++) {
    float ex = expf(sc[h]);
    exbuf[(size_t)e * H + h] = ex;
    atomicAdd(&denom[(size_t)dst * H + h], ex);
  }
}

// ---------------- edge scatter pass: acc[dst] += xl[src] * alpha ----------------
template<int D, int H>
__global__ __launch_bounds__(256) void edge_scatter_k(
    const int* __restrict__ ei, const float* __restrict__ xl,
    const float* __restrict__ exbuf, const float* __restrict__ denom,
    float* __restrict__ acc) {
  constexpr int C = D / H;
  int e = blockIdx.x * 256 + threadIdx.x;
  if (e >= NE) return;
  int src = ei[e], dst = ei[NE + e];
  float alpha[H];
#pragma unroll
  for (int h = 0; h < H; h++)
    alpha[h] = exbuf[(size_t)e * H + h] / (denom[(size_t)dst * H + h] + 1e-16f);
  const float4* xls = (const float4*)(xl + (size_t)src * D);
  float* ad = acc + (size_t)dst * D;
#pragma unroll
  for (int q = 0; q < D / 4; q++) {
    float4 a = xls[q];
    float al = alpha[(4 * q) / C];
    atomicAdd(&ad[4 * q + 0], a.x * al);
    atomicAdd(&ad[4 * q + 1], a.y * al);
    atomicAdd(&ad[4 * q + 2], a.z * al);
    atomicAdd(&ad[4 * q + 3], a.w * al);
  }
}

// ---------------- node update: bias + BN + skip + ELU ----------------
template<int D>
__global__ __launch_bounds__(256) void node_update_k(
    const float* __restrict__ acc, const float* __restrict__ bias,
    const float* __restrict__ gamma, const float* __restrict__ beta,
    const float* __restrict__ mean, const float* __restrict__ var,
    const float* __restrict__ xp, float* __restrict__ hout, int n) {
  size_t i = (size_t)blockIdx.x * 256 + threadIdx.x;
  if (i >= (size_t)n * D) return;
  int c = (int)(i % D);
  float v = acc[i] + bias[c];
  v = (v - mean[c]) * gamma[c] * rsqrtf(var[c] + 1e-5f) + beta[c];
  v += xp[i];
  hout[i] = v > 0.f ? v : expm1f(v);
}

// ---------------- pooling ----------------
__device__ inline unsigned fkey(float f) {
  unsigned u = __float_as_uint(f);
  return (u & 0x80000000u) ? ~u : (u | 0x80000000u);
}
__device__ inline float funkey(unsigned k) {
  unsigned u = (k & 0x80000000u) ? (k & 0x7FFFFFFFu) : ~k;
  return __uint_as_float(u);
}

__global__ __launch_bounds__(256) void pool_init_k(float* sums, unsigned* maxk, int* cnt) {
  int t = blockIdx.x * 256 + threadIdx.x;
  if (t < NG * DD2) { sums[t] = 0.f; maxk[t] = fkey(-INFINITY); }
  if (t < NG) cnt[t] = 0;
}

__global__ __launch_bounds__(256) void pool_accum_k(const float* __restrict__ h2,
    const int* __restrict__ batch, float* sums, unsigned* maxk, int* cnt) {
  int node = blockIdx.x * 256 + threadIdx.x;
  if (node >= NN) return;
  int g = batch[node];
  atomicAdd(&cnt[g], 1);
  const float* hp = h2 + (size_t)node * DD2;
#pragma unroll
  for (int c = 0; c < DD2; c++) {
    float v = hp[c];
    atomicAdd(&sums[g * DD2 + c], v);
    atomicMax(&maxk[g * DD2 + c], fkey(v));
  }
}

__global__ void classify_k(const float* __restrict__ sums, const unsigned* __restrict__ maxk,
    const int* __restrict__ cnt, const float* __restrict__ W,
    const float* __restrict__ b, float* __restrict__ out) {
  int t = threadIdx.x;
  if (t >= NG * NCLS) return;
  int g = t / NCLS, k = t % NCLS;
  float accv = b[k];
  float inv = 1.f / fmaxf((float)cnt[g], 1.f);
  for (int j = 0; j < DD2; j++) accv += (sums[g * DD2 + j] * inv) * W[j * NCLS + k];
  for (int j = 0; j < DD2; j++) {
    float mx = funkey(maxk[g * DD2 + j]);
    if (mx < -3e38f) mx = 0.f;
    accv += mx * W[(DD2 + j) * NCLS + k];
  }
  out[g * NCLS + k] = accv;
}

// ---------------- launch ----------------
extern "C" void kernel_launch(void* const* d_in, const int* in_sizes, int n_in,
                              void* d_out, int out_size, void* d_ws, size_t ws_size,
                              hipStream_t stream) {
  (void)in_sizes; (void)n_in; (void)out_size; (void)ws_size;
  const float* x       = (const float*)d_in[0];
  const float* eattr   = (const float*)d_in[1];
  const int*   ei      = (const int*)d_in[2];
  const int*   batch   = (const int*)d_in[3];
  const float* c1_Wl   = (const float*)d_in[4];
  const float* c1_bl   = (const float*)d_in[5];
  const float* c1_Wr   = (const float*)d_in[6];
  const float* c1_br   = (const float*)d_in[7];
  const float* c1_We   = (const float*)d_in[8];
  const float* c1_att  = (const float*)d_in[9];
  const float* c1_bias = (const float*)d_in[10];
  const float* bn1_g   = (const float*)d_in[11];
  const float* bn1_b   = (const float*)d_in[12];
  const float* bn1_m   = (const float*)d_in[13];
  const float* bn1_v   = (const float*)d_in[14];
  const float* sp1_W   = (const float*)d_in[15];
  const float* sp1_b   = (const float*)d_in[16];
  const float* c2_Wl   = (const float*)d_in[17];
  const float* c2_bl   = (const float*)d_in[18];
  const float* c2_Wr   = (const float*)d_in[19];
  const float* c2_br   = (const float*)d_in[20];
  const float* c2_We   = (const float*)d_in[21];
  const float* c2_att  = (const float*)d_in[22];
  const float* c2_bias = (const float*)d_in[23];
  const float* bn2_g   = (const float*)d_in[24];
  const float* bn2_b   = (const float*)d_in[25];
  const float* bn2_m   = (const float*)d_in[26];
  const float* bn2_v   = (const float*)d_in[27];
  const float* sp2_W   = (const float*)d_in[28];
  const float* sp2_b   = (const float*)d_in[29];
  const float* cls_W   = (const float*)d_in[30];
  const float* cls_b   = (const float*)d_in[31];

  float* w    = (float*)d_ws;
  float* A    = w;                              // N*64: XL1 / XL2
  float* B    = A + (size_t)NN * DD1;           // N*64: XR1 / XR2 / h2
  float* Cb   = B + (size_t)NN * DD1;           // N*64: XP1 / XP2
  float* Db   = Cb + (size_t)NN * DD1;          // N*64: acc1 -> h (in place)
  float* EX   = Db + (size_t)NN * DD1;          // E*2: ex1; later ex2 (first E) + acc2
  float* DEN  = EX + (size_t)NE * 2;            // N*2: denom1; later denom2 (first N)
  float* PS   = DEN + (size_t)NN * 2;           // NG*32 pool sums
  unsigned* PM = (unsigned*)(PS + NG * DD2);    // NG*32 pool max keys
  int* PC     = (int*)(PM + NG * DD2);          // NG counts
  float* acc2 = EX + NE;                        // N*32

  hipMemsetAsync(Db, 0, (size_t)NN * DD1 * sizeof(float), stream);
  hipMemsetAsync(DEN, 0, (size_t)NN * 2 * sizeof(float), stream);

  int tgrid = (NN + 31) / 32;
  int egrid = (NE + 255) / 256;

  // ---- layer 1 ----
  transform_k<FIN, DD1><<<tgrid, 256, 0, stream>>>(x, c1_Wl, c1_bl, A, NN);
  transform_k<FIN, DD1><<<tgrid, 256, 0, stream>>>(x, c1_Wr, c1_br, B, NN);
  transform_k<FIN, DD1><<<tgrid, 256, 0, stream>>>(x, sp1_W, sp1_b, Cb, NN);
  edge_score_k<DD1, HH1><<<egrid, 256, 0, stream>>>(ei, eattr, A, B, c1_We, c1_att, EX, DEN);
  edge_scatter_k<DD1, HH1><<<egrid, 256, 0, stream>>>(ei, A, EX, DEN, Db);
  node_update_k<DD1><<<(NN * DD1 + 255) / 256, 256, 0, stream>>>(
      Db, c1_bias, bn1_g, bn1_b, bn1_m, bn1_v, Cb, Db, NN);

  // ---- layer 2 ----
  hipMemsetAsync(acc2, 0, (size_t)NN * DD2 * sizeof(float), stream);
  hipMemsetAsync(DEN, 0, (size_t)NN * sizeof(float), stream);
  transform_k<DD1, DD2><<<tgrid, 256, 0, stream>>>(Db, c2_Wl, c2_bl, A, NN);
  transform_k<DD1, DD2><<<tgrid, 256, 0, stream>>>(Db, c2_Wr, c2_br, B, NN);
  transform_k<DD1, DD2><<<tgrid, 256, 0, stream>>>(Db, sp2_W, sp2_b, Cb, NN);
  edge_score_k<DD2, 1><<<egrid, 256, 0, stream>>>(ei, eattr, A, B, c2_We, c2_att, EX, DEN);
  edge_scatter_k<DD2, 1><<<egrid, 256, 0, stream>>>(ei, A, EX, DEN, acc2);
  node_update_k<DD2><<<(NN * DD2 + 255) / 256, 256, 0, stream>>>(
      acc2, c2_bias, bn2_g, bn2_b, bn2_m, bn2_v, Cb, B, NN);

  // ---- pooling + classifier ----
  pool_init_k<<<(NG * DD2 + 255) / 256, 256, 0, stream>>>(PS, PM, PC);
  pool_accum_k<<<(NN + 255) / 256, 256, 0, stream>>>(B, batch, PS, PM, PC);
  classify_k<<<1, 128, 0, stream>>>(PS, PM, PC, cls_W, cls_b, (float*)d_out);
}

// Round 3
// 1620.301 us; speedup vs baseline: 5.6886x; 5.6886x over previous
//
#include <hip/hip_runtime.h>
#include <math.h>

#define NN 50000
#define NE 1600000
#define FIN 128
#define EDIM 16
#define DD1 64
#define HH1 2
#define DD2 32
#define NG 64
#define NCLS 2
#define SCAN_CHUNK 512
#define NB_SCAN ((NN + SCAN_CHUNK - 1) / SCAN_CHUNK)   // 98

// ---------------- node transform: out[n, OUT] = X[n, IN] @ W + b ----------------
template<int IN, int OUT>
__global__ __launch_bounds__(256) void transform_k(const float* __restrict__ X,
    const float* __restrict__ W, const float* __restrict__ b,
    float* __restrict__ out, int n) {
  constexpr int NPB = 32;            // nodes per block
  constexpr int TPN = 256 / NPB;     // 8 threads per node
  constexpr int CPT = OUT / TPN;     // cols per thread
  __shared__ float sW[IN * OUT];
  __shared__ float sX[NPB * IN];
  int t = threadIdx.x;
  int nodeBase = blockIdx.x * NPB;
  for (int i = t; i < IN * OUT; i += 256) sW[i] = W[i];
  constexpr int XE = NPB * IN / 4;
  const float4* X4 = (const float4*)X;
  float4* sX4 = (float4*)sX;
  for (int i = t; i < XE; i += 256) {
    int node = nodeBase + i / (IN / 4);
    sX4[i] = (node < n) ? X4[(size_t)node * (IN / 4) + i % (IN / 4)]
                        : make_float4(0.f, 0.f, 0.f, 0.f);
  }
  __syncthreads();
  int ln = t / TPN;
  int cb = (t % TPN) * CPT;
  int node = nodeBase + ln;
  float acc[CPT];
#pragma unroll
  for (int j = 0; j < CPT; j++) acc[j] = b[cb + j];
  const float* xs = &sX[ln * IN];
  for (int k = 0; k < IN; k++) {
    float xv = xs[k];
#pragma unroll
    for (int j = 0; j < CPT; j++) acc[j] += xv * sW[k * OUT + cb + j];
  }
  if (node < n) {
#pragma unroll
    for (int j = 0; j < CPT; j++) out[(size_t)node * OUT + cb + j] = acc[j];
  }
}

// ---------------- CSR build ----------------
__global__ __launch_bounds__(256) void hist_k(const int* __restrict__ ei, int* __restrict__ deg) {
  int e = blockIdx.x * 256 + threadIdx.x;
  if (e >= NE) return;
  atomicAdd(&deg[ei[NE + e]], 1);
}

__global__ __launch_bounds__(256) void scan_bsum_k(const int* __restrict__ deg,
                                                   int* __restrict__ bsum, int n) {
  __shared__ int s[256];
  int b = blockIdx.x, t = threadIdx.x;
  int i0 = b * SCAN_CHUNK + 2 * t, i1 = i0 + 1;
  int v = ((i0 < n) ? deg[i0] : 0) + ((i1 < n) ? deg[i1] : 0);
  s[t] = v;
  __syncthreads();
  for (int off = 128; off; off >>= 1) {
    if (t < off) s[t] += s[t + off];
    __syncthreads();
  }
  if (t == 0) bsum[b] = s[0];
}

__global__ void scan_boff_k(const int* __restrict__ bsum, int* __restrict__ boff, int nb) {
  if (threadIdx.x == 0) {
    int run = 0;
    for (int i = 0; i < nb; i++) { int v = bsum[i]; boff[i] = run; run += v; }
  }
}

__global__ __launch_bounds__(256) void scan_rowptr_k(const int* __restrict__ deg,
    const int* __restrict__ boff, int* __restrict__ rowptr, int n) {
  __shared__ int s[256];
  int b = blockIdx.x, t = threadIdx.x;
  int i0 = b * SCAN_CHUNK + 2 * t, i1 = i0 + 1;
  int d0 = (i0 < n) ? deg[i0] : 0;
  int d1 = (i1 < n) ? deg[i1] : 0;
  s[t] = d0 + d1;
  __syncthreads();
  for (int off = 1; off < 256; off <<= 1) {
    int add = (t >= off) ? s[t - off] : 0;
    __syncthreads();
    s[t] += add;
    __syncthreads();
  }
  int excl = (t == 0) ? 0 : s[t - 1];
  int o = boff[b] + excl;
  if (i0 < n) rowptr[i0] = o;
  if (i1 < n) rowptr[i1] = o + d0;
}

__global__ __launch_bounds__(256) void fill_k(const int* __restrict__ ei,
    const int* __restrict__ rowptr, int* __restrict__ fillc,
    int* __restrict__ srcs_perm, int* __restrict__ posmap) {
  int e = blockIdx.x * 256 + threadIdx.x;
  if (e >= NE) return;
  int src = ei[e], dst = ei[NE + e];
  int pos = rowptr[dst] + atomicAdd(&fillc[dst], 1);
  srcs_perm[pos] = src;
  posmap[e] = pos;
}

// ---------------- edge score pass: ex_perm[posmap[e]*H+h] = exp(score) ----------------
template<int D, int H>
__global__ __launch_bounds__(256) void score_k(
    const int* __restrict__ ei, const float* __restrict__ eattr,
    const float* __restrict__ xl, const float* __restrict__ xr,
    const float* __restrict__ We, const float* __restrict__ att,
    const int* __restrict__ posmap, float* __restrict__ ex_perm) {
  constexpr int C = D / H;
  __shared__ float sWe[EDIM * D];
  __shared__ float sAtt[D];
  int t = threadIdx.x;
  for (int i = t; i < EDIM * D; i += 256) sWe[i] = We[i];
  for (int i = t; i < D; i += 256) sAtt[i] = att[i];
  __syncthreads();
  int e = blockIdx.x * 256 + t;
  if (e >= NE) return;
  int src = ei[e], dst = ei[NE + e];
  float ea[EDIM];
  const float4* ea4 = (const float4*)(eattr + (size_t)e * EDIM);
#pragma unroll
  for (int q = 0; q < EDIM / 4; q++) {
    float4 v = ea4[q];
    ea[4 * q] = v.x; ea[4 * q + 1] = v.y; ea[4 * q + 2] = v.z; ea[4 * q + 3] = v.w;
  }
  const float4* xls = (const float4*)(xl + (size_t)src * D);
  const float4* xrd = (const float4*)(xr + (size_t)dst * D);
  float sc[H];
#pragma unroll
  for (int h = 0; h < H; h++) sc[h] = 0.f;
#pragma unroll
  for (int q = 0; q < D / 4; q++) {
    float4 a = xls[q], r = xrd[q];
    float av[4] = {a.x, a.y, a.z, a.w};
    float rv[4] = {r.x, r.y, r.z, r.w};
#pragma unroll
    for (int j = 0; j < 4; j++) {
      int hc = 4 * q + j;
      float ef = 0.f;
#pragma unroll
      for (int k = 0; k < EDIM; k++) ef += ea[k] * sWe[k * D + hc];
      float m = av[j] + rv[j] + ef;
      m = m > 0.f ? m : 0.2f * m;
      sc[hc / C] += m * sAtt[hc];
    }
  }
  int pos = posmap[e];
#pragma unroll
  for (int h = 0; h < H; h++) ex_perm[(size_t)pos * H + h] = expf(sc[h]);
}

// ---------------- gather: per-dst softmax + weighted sum + BN/skip/ELU ----------------
template<int D, int H>
__global__ __launch_bounds__(256) void gather_k(
    const int* __restrict__ rowptr, const int* __restrict__ deg,
    const int* __restrict__ srcs_perm, const float* __restrict__ ex_perm,
    const float* __restrict__ xl, const float* __restrict__ bias,
    const float* __restrict__ gamma, const float* __restrict__ beta,
    const float* __restrict__ mean, const float* __restrict__ var,
    const float* __restrict__ xp, float* __restrict__ hout) {
  constexpr int C = D / H;
  int gid = (blockIdx.x * 256 + threadIdx.x) / D;   // dst node
  int lane = threadIdx.x % D;                        // channel
  if (gid >= NN) return;
  int start = rowptr[gid];
  int len = deg[gid];
  // phase 1: softmax denominator per head
  float den[H];
#pragma unroll
  for (int h = 0; h < H; h++) den[h] = 0.f;
  for (int j = lane; j < len; j += D) {
#pragma unroll
    for (int h = 0; h < H; h++) den[h] += ex_perm[(size_t)(start + j) * H + h];
  }
#pragma unroll
  for (int off = D / 2; off; off >>= 1) {
#pragma unroll
    for (int h = 0; h < H; h++) den[h] += __shfl_xor(den[h], off, D);
  }
  float inv[H];
#pragma unroll
  for (int h = 0; h < H; h++) inv[h] = 1.f / (den[h] + 1e-16f);
  // phase 2: weighted gather, channel per lane
  int h = lane / C;
  float myinv = inv[h];
  float acc = 0.f;
  for (int j = 0; j < len; j++) {
    int src = srcs_perm[start + j];
    float exv = ex_perm[(size_t)(start + j) * H + h];
    acc += xl[(size_t)src * D + lane] * (exv * myinv);
  }
  // epilogue: bias + BN + skip + ELU
  float v = acc + bias[lane];
  v = (v - mean[lane]) * gamma[lane] * rsqrtf(var[lane] + 1e-5f) + beta[lane];
  v += xp[(size_t)gid * D + lane];
  hout[(size_t)gid * D + lane] = v > 0.f ? v : expm1f(v);
}

// ---------------- pooling ----------------
__device__ inline unsigned fkey(float f) {
  unsigned u = __float_as_uint(f);
  return (u & 0x80000000u) ? ~u : (u | 0x80000000u);
}
__device__ inline float funkey(unsigned k) {
  unsigned u = (k & 0x80000000u) ? (k & 0x7FFFFFFFu) : ~k;
  return __uint_as_float(u);
}

__global__ __launch_bounds__(256) void pool_init_k(float* sums, unsigned* maxk, int* cnt) {
  int t = blockIdx.x * 256 + threadIdx.x;
  if (t < NG * DD2) { sums[t] = 0.f; maxk[t] = fkey(-INFINITY); }
  if (t < NG) cnt[t] = 0;
}

__global__ __launch_bounds__(256) void pool_accum_k(const float* __restrict__ h2,
    const int* __restrict__ batch, float* sums, unsigned* maxk, int* cnt) {
  int node = blockIdx.x * 256 + threadIdx.x;
  if (node >= NN) return;
  int g = batch[node];
  atomicAdd(&cnt[g], 1);
  const float* hp = h2 + (size_t)node * DD2;
#pragma unroll
  for (int c = 0; c < DD2; c++) {
    float v = hp[c];
    atomicAdd(&sums[g * DD2 + c], v);
    atomicMax(&maxk[g * DD2 + c], fkey(v));
  }
}

__global__ void classify_k(const float* __restrict__ sums, const unsigned* __restrict__ maxk,
    const int* __restrict__ cnt, const float* __restrict__ W,
    const float* __restrict__ b, float* __restrict__ out) {
  int t = threadIdx.x;
  if (t >= NG * NCLS) return;
  int g = t / NCLS, k = t % NCLS;
  float accv = b[k];
  float inv = 1.f / fmaxf((float)cnt[g], 1.f);
  for (int j = 0; j < DD2; j++) accv += (sums[g * DD2 + j] * inv) * W[j * NCLS + k];
  for (int j = 0; j < DD2; j++) {
    float mx = funkey(maxk[g * DD2 + j]);
    if (mx < -3e38f) mx = 0.f;
    accv += mx * W[(DD2 + j) * NCLS + k];
  }
  out[g * NCLS + k] = accv;
}

// ---------------- launch ----------------
extern "C" void kernel_launch(void* const* d_in, const int* in_sizes, int n_in,
                              void* d_out, int out_size, void* d_ws, size_t ws_size,
                              hipStream_t stream) {
  (void)in_sizes; (void)n_in; (void)out_size; (void)ws_size;
  const float* x       = (const float*)d_in[0];
  const float* eattr   = (const float*)d_in[1];
  const int*   ei      = (const int*)d_in[2];
  const int*   batch   = (const int*)d_in[3];
  const float* c1_Wl   = (const float*)d_in[4];
  const float* c1_bl   = (const float*)d_in[5];
  const float* c1_Wr   = (const float*)d_in[6];
  const float* c1_br   = (const float*)d_in[7];
  const float* c1_We   = (const float*)d_in[8];
  const float* c1_att  = (const float*)d_in[9];
  const float* c1_bias = (const float*)d_in[10];
  const float* bn1_g   = (const float*)d_in[11];
  const float* bn1_b   = (const float*)d_in[12];
  const float* bn1_m   = (const float*)d_in[13];
  const float* bn1_v   = (const float*)d_in[14];
  const float* sp1_W   = (const float*)d_in[15];
  const float* sp1_b   = (const float*)d_in[16];
  const float* c2_Wl   = (const float*)d_in[17];
  const float* c2_bl   = (const float*)d_in[18];
  const float* c2_Wr   = (const float*)d_in[19];
  const float* c2_br   = (const float*)d_in[20];
  const float* c2_We   = (const float*)d_in[21];
  const float* c2_att  = (const float*)d_in[22];
  const float* c2_bias = (const float*)d_in[23];
  const float* bn2_g   = (const float*)d_in[24];
  const float* bn2_b   = (const float*)d_in[25];
  const float* bn2_m   = (const float*)d_in[26];
  const float* bn2_v   = (const float*)d_in[27];
  const float* sp2_W   = (const float*)d_in[28];
  const float* sp2_b   = (const float*)d_in[29];
  const float* cls_W   = (const float*)d_in[30];
  const float* cls_b   = (const float*)d_in[31];

  float* w     = (float*)d_ws;
  float* A     = w;                                 // N*64: xl (both layers)
  float* B     = A + (size_t)NN * DD1;              // N*64: xr
  float* Cb    = B + (size_t)NN * DD1;              // N*64: xp (skip)
  float* H1    = Cb + (size_t)NN * DD1;             // N*64: h1; then h2 (N*32)
  float* EXP   = H1 + (size_t)NN * DD1;             // E*2: exp scores (CSR order)
  int* srcs    = (int*)(EXP + (size_t)NE * HH1);    // E
  int* posm    = srcs + NE;                         // E
  int* rowptr  = posm + NE;                         // N
  int* deg     = rowptr + NN;                       // N
  int* fillc   = deg + NN;                          // N
  int* bsum    = fillc + NN;                        // NB_SCAN
  int* boff    = bsum + NB_SCAN;                    // NB_SCAN
  float* PS    = (float*)(boff + NB_SCAN);          // NG*32
  unsigned* PM = (unsigned*)(PS + NG * DD2);        // NG*32
  int* PC      = (int*)(PM + NG * DD2);             // NG

  int tgrid = (NN + 31) / 32;
  int egrid = (NE + 255) / 256;

  // ---- CSR build (shared by both layers) ----
  hipMemsetAsync(deg, 0, (size_t)NN * sizeof(int), stream);
  hipMemsetAsync(fillc, 0, (size_t)NN * sizeof(int), stream);
  hist_k<<<egrid, 256, 0, stream>>>(ei, deg);
  scan_bsum_k<<<NB_SCAN, 256, 0, stream>>>(deg, bsum, NN);
  scan_boff_k<<<1, 64, 0, stream>>>(bsum, boff, NB_SCAN);
  scan_rowptr_k<<<NB_SCAN, 256, 0, stream>>>(deg, boff, rowptr, NN);
  fill_k<<<egrid, 256, 0, stream>>>(ei, rowptr, fillc, srcs, posm);

  // ---- layer 1 ----
  transform_k<FIN, DD1><<<tgrid, 256, 0, stream>>>(x, c1_Wl, c1_bl, A, NN);
  transform_k<FIN, DD1><<<tgrid, 256, 0, stream>>>(x, c1_Wr, c1_br, B, NN);
  transform_k<FIN, DD1><<<tgrid, 256, 0, stream>>>(x, sp1_W, sp1_b, Cb, NN);
  score_k<DD1, HH1><<<egrid, 256, 0, stream>>>(ei, eattr, A, B, c1_We, c1_att, posm, EXP);
  gather_k<DD1, HH1><<<(NN * DD1 + 255) / 256, 256, 0, stream>>>(
      rowptr, deg, srcs, EXP, A, c1_bias, bn1_g, bn1_b, bn1_m, bn1_v, Cb, H1);

  // ---- layer 2 ----
  transform_k<DD1, DD2><<<tgrid, 256, 0, stream>>>(H1, c2_Wl, c2_bl, A, NN);
  transform_k<DD1, DD2><<<tgrid, 256, 0, stream>>>(H1, c2_Wr, c2_br, B, NN);
  transform_k<DD1, DD2><<<tgrid, 256, 0, stream>>>(H1, sp2_W, sp2_b, Cb, NN);
  score_k<DD2, 1><<<egrid, 256, 0, stream>>>(ei, eattr, A, B, c2_We, c2_att, posm, EXP);
  gather_k<DD2, 1><<<(NN * DD2 + 255) / 256, 256, 0, stream>>>(
      rowptr, deg, srcs, EXP, A, c2_bias, bn2_g, bn2_b, bn2_m, bn2_v, Cb, H1);

  // ---- pooling + classifier ----
  pool_init_k<<<(NG * DD2 + 255) / 256, 256, 0, stream>>>(PS, PM, PC);
  pool_accum_k<<<(NN + 255) / 256, 256, 0, stream>>>(H1, batch, PS, PM, PC);
  classify_k<<<1, 128, 0, stream>>>(PS, PM, PC, cls_W, cls_b, (float*)d_out);
}

// Round 6
// 1154.354 us; speedup vs baseline: 7.9848x; 1.4036x over previous
//
#include <hip/hip_runtime.h>
#include <math.h>

#define NN 50000
#define NE 1600000
#define FIN 128
#define EDIM 16
#define DD1 64
#define HH1 2
#define DD2 32
#define NG 64
#define NCLS 2
#define SCAN_CHUNK 512
#define NB_SCAN ((NN + SCAN_CHUNK - 1) / SCAN_CHUNK)   // 98

// ---------------- node transform: out[n, OUT] = X[n, IN] @ W + b ----------------
template<int IN, int OUT>
__global__ __launch_bounds__(256) void transform_k(const float* __restrict__ X,
    const float* __restrict__ W, const float* __restrict__ b,
    float* __restrict__ out, int n) {
  constexpr int NPB = 32;            // nodes per block
  constexpr int TPN = 256 / NPB;     // 8 threads per node
  constexpr int CPT = OUT / TPN;     // cols per thread
  __shared__ float sW[IN * OUT];
  __shared__ float sX[NPB * IN];
  int t = threadIdx.x;
  int nodeBase = blockIdx.x * NPB;
  for (int i = t; i < IN * OUT; i += 256) sW[i] = W[i];
  constexpr int XE = NPB * IN / 4;
  const float4* X4 = (const float4*)X;
  float4* sX4 = (float4*)sX;
  for (int i = t; i < XE; i += 256) {
    int node = nodeBase + i / (IN / 4);
    sX4[i] = (node < n) ? X4[(size_t)node * (IN / 4) + i % (IN / 4)]
                        : make_float4(0.f, 0.f, 0.f, 0.f);
  }
  __syncthreads();
  int ln = t / TPN;
  int cb = (t % TPN) * CPT;
  int node = nodeBase + ln;
  float acc[CPT];
#pragma unroll
  for (int j = 0; j < CPT; j++) acc[j] = b[cb + j];
  const float* xs = &sX[ln * IN];
  for (int k = 0; k < IN; k++) {
    float xv = xs[k];
#pragma unroll
    for (int j = 0; j < CPT; j++) acc[j] += xv * sW[k * OUT + cb + j];
  }
  if (node < n) {
#pragma unroll
    for (int j = 0; j < CPT; j++) out[(size_t)node * OUT + cb + j] = acc[j];
  }
}

// ---------------- CSR build ----------------
__global__ __launch_bounds__(256) void hist_k(const int* __restrict__ ei, int* __restrict__ deg) {
  int e = blockIdx.x * 256 + threadIdx.x;
  if (e >= NE) return;
  atomicAdd(&deg[ei[NE + e]], 1);
}

__global__ __launch_bounds__(256) void scan_bsum_k(const int* __restrict__ deg,
                                                   int* __restrict__ bsum, int n) {
  __shared__ int s[256];
  int b = blockIdx.x, t = threadIdx.x;
  int i0 = b * SCAN_CHUNK + 2 * t, i1 = i0 + 1;
  int v = ((i0 < n) ? deg[i0] : 0) + ((i1 < n) ? deg[i1] : 0);
  s[t] = v;
  __syncthreads();
  for (int off = 128; off; off >>= 1) {
    if (t < off) s[t] += s[t + off];
    __syncthreads();
  }
  if (t == 0) bsum[b] = s[0];
}

__global__ void scan_boff_k(const int* __restrict__ bsum, int* __restrict__ boff, int nb) {
  if (threadIdx.x == 0) {
    int run = 0;
    for (int i = 0; i < nb; i++) { int v = bsum[i]; boff[i] = run; run += v; }
  }
}

__global__ __launch_bounds__(256) void scan_rowptr_k(const int* __restrict__ deg,
    const int* __restrict__ boff, int* __restrict__ rowptr, int n) {
  __shared__ int s[256];
  int b = blockIdx.x, t = threadIdx.x;
  int i0 = b * SCAN_CHUNK + 2 * t, i1 = i0 + 1;
  int d0 = (i0 < n) ? deg[i0] : 0;
  int d1 = (i1 < n) ? deg[i1] : 0;
  s[t] = d0 + d1;
  __syncthreads();
  for (int off = 1; off < 256; off <<= 1) {
    int add = (t >= off) ? s[t - off] : 0;
    __syncthreads();
    s[t] += add;
    __syncthreads();
  }
  int excl = (t == 0) ? 0 : s[t - 1];
  int o = boff[b] + excl;
  if (i0 < n) rowptr[i0] = o;
  if (i1 < n) rowptr[i1] = o + d0;
}

__global__ __launch_bounds__(256) void fill_k(const int* __restrict__ ei,
    const int* __restrict__ rowptr, int* __restrict__ fillc,
    int* __restrict__ srcs_perm, int* __restrict__ posmap) {
  int e = blockIdx.x * 256 + threadIdx.x;
  if (e >= NE) return;
  int src = ei[e], dst = ei[NE + e];
  int pos = rowptr[dst] + atomicAdd(&fillc[dst], 1);
  srcs_perm[pos] = src;
  posmap[e] = pos;
}

// ---------------- edge score pass: ex_perm[posmap[e]*H+h] = exp(score) ----------------
template<int D, int H>
__global__ __launch_bounds__(256) void score_k(
    const int* __restrict__ ei, const float* __restrict__ eattr,
    const float* __restrict__ xl, const float* __restrict__ xr,
    const float* __restrict__ We, const float* __restrict__ att,
    const int* __restrict__ posmap, float* __restrict__ ex_perm) {
  constexpr int C = D / H;
  __shared__ float sWe[EDIM * D];
  __shared__ float sAtt[D];
  int t = threadIdx.x;
  for (int i = t; i < EDIM * D; i += 256) sWe[i] = We[i];
  for (int i = t; i < D; i += 256) sAtt[i] = att[i];
  __syncthreads();
  int e = blockIdx.x * 256 + t;
  if (e >= NE) return;
  int src = ei[e], dst = ei[NE + e];
  float ea[EDIM];
  const float4* ea4 = (const float4*)(eattr + (size_t)e * EDIM);
#pragma unroll
  for (int q = 0; q < EDIM / 4; q++) {
    float4 v = ea4[q];
    ea[4 * q] = v.x; ea[4 * q + 1] = v.y; ea[4 * q + 2] = v.z; ea[4 * q + 3] = v.w;
  }
  const float4* xls = (const float4*)(xl + (size_t)src * D);
  const float4* xrd = (const float4*)(xr + (size_t)dst * D);
  float sc[H];
#pragma unroll
  for (int h = 0; h < H; h++) sc[h] = 0.f;
#pragma unroll
  for (int q = 0; q < D / 4; q++) {
    float4 a = xls[q], r = xrd[q];
    float av[4] = {a.x, a.y, a.z, a.w};
    float rv[4] = {r.x, r.y, r.z, r.w};
#pragma unroll
    for (int j = 0; j < 4; j++) {
      int hc = 4 * q + j;
      float ef = 0.f;
#pragma unroll
      for (int k = 0; k < EDIM; k++) ef += ea[k] * sWe[k * D + hc];
      float m = av[j] + rv[j] + ef;
      m = m > 0.f ? m : 0.2f * m;
      sc[hc / C] += m * sAtt[hc];
    }
  }
  int pos = posmap[e];
#pragma unroll
  for (int h = 0; h < H; h++) ex_perm[(size_t)pos * H + h] = expf(sc[h]);
}

// ---------------- gather: per-dst softmax + weighted sum + BN/skip/ELU ----------------
template<int D, int H>
__global__ __launch_bounds__(256) void gather_k(
    const int* __restrict__ rowptr, const int* __restrict__ deg,
    const int* __restrict__ srcs_perm, const float* __restrict__ ex_perm,
    const float* __restrict__ xl, const float* __restrict__ bias,
    const float* __restrict__ gamma, const float* __restrict__ beta,
    const float* __restrict__ mean, const float* __restrict__ var,
    const float* __restrict__ xp, float* __restrict__ hout) {
  constexpr int C = D / H;
  int gid = (blockIdx.x * 256 + threadIdx.x) / D;   // dst node
  int lane = threadIdx.x % D;                        // channel
  if (gid >= NN) return;
  int start = rowptr[gid];
  int len = deg[gid];
  // phase 1: softmax denominator per head
  float den[H];
#pragma unroll
  for (int h = 0; h < H; h++) den[h] = 0.f;
  for (int j = lane; j < len; j += D) {
#pragma unroll
    for (int h = 0; h < H; h++) den[h] += ex_perm[(size_t)(start + j) * H + h];
  }
#pragma unroll
  for (int off = D / 2; off; off >>= 1) {
#pragma unroll
    for (int h = 0; h < H; h++) den[h] += __shfl_xor(den[h], off, D);
  }
  float inv[H];
#pragma unroll
  for (int h = 0; h < H; h++) inv[h] = 1.f / (den[h] + 1e-16f);
  // phase 2: weighted gather, channel per lane
  int h = lane / C;
  float myinv = inv[h];
  float acc = 0.f;
  for (int j = 0; j < len; j++) {
    int src = srcs_perm[start + j];
    float exv = ex_perm[(size_t)(start + j) * H + h];
    acc += xl[(size_t)src * D + lane] * (exv * myinv);
  }
  // epilogue: bias + BN + skip + ELU
  float v = acc + bias[lane];
  v = (v - mean[lane]) * gamma[lane] * rsqrtf(var[lane] + 1e-5f) + beta[lane];
  v += xp[(size_t)gid * D + lane];
  hout[(size_t)gid * D + lane] = v > 0.f ? v : expm1f(v);
}

// ---------------- pooling ----------------
__device__ inline unsigned fkey(float f) {
  unsigned u = __float_as_uint(f);
  return (u & 0x80000000u) ? ~u : (u | 0x80000000u);
}
__device__ inline float funkey(unsigned k) {
  unsigned u = (k & 0x80000000u) ? (k & 0x7FFFFFFFu) : ~k;
  return __uint_as_float(u);
}

__global__ __launch_bounds__(256) void pool_init_k(float* sums, unsigned* maxk, int* cnt) {
  int t = blockIdx.x * 256 + threadIdx.x;
  if (t < NG * DD2) { sums[t] = 0.f; maxk[t] = fkey(-INFINITY); }
  if (t < NG) cnt[t] = 0;
}

// hierarchical: LDS partials per (graph-in-span, channel), then few global atomics.
#define PSPAN 16
__global__ __launch_bounds__(256) void pool_accum_k(const float* __restrict__ h2,
    const int* __restrict__ batch, float* sums, unsigned* maxk, int* cnt) {
  __shared__ float ls[PSPAN][DD2];
  __shared__ unsigned lm[PSPAN][DD2];
  __shared__ int lc[PSPAN];
  int base = blockIdx.x * 256;
  int t = threadIdx.x;
  int c = t % DD2;       // channel
  int nsub = t / DD2;    // 0..7
  int lastNode = min(base + 256, NN) - 1;
  int gmin = batch[base];
  int gmax = batch[lastNode];
  for (int gbase = gmin; gbase <= gmax; gbase += PSPAN) {
    int span = min(PSPAN, gmax - gbase + 1);
    for (int i = t; i < span * DD2; i += 256) {
      ls[i / DD2][i % DD2] = 0.f;
      lm[i / DD2][i % DD2] = fkey(-INFINITY);
    }
    if (t < span) lc[t] = 0;
    __syncthreads();
    for (int nnode = base + nsub; nnode < base + 256 && nnode < NN; nnode += 8) {
      int g = batch[nnode] - gbase;
      if (g >= 0 && g < span) {
        float v = h2[(size_t)nnode * DD2 + c];
        atomicAdd(&ls[g][c], v);
        atomicMax(&lm[g][c], fkey(v));
        if (c == 0) atomicAdd(&lc[g], 1);
      }
    }
    __syncthreads();
    for (int i = t; i < span * DD2; i += 256) {
      int g = gbase + i / DD2;
      atomicAdd(&sums[g * DD2 + i % DD2], ls[i / DD2][i % DD2]);
      atomicMax(&maxk[g * DD2 + i % DD2], lm[i / DD2][i % DD2]);
    }
    if (t < span) atomicAdd(&cnt[gbase + t], lc[t]);
    __syncthreads();
  }
}

__global__ void classify_k(const float* __restrict__ sums, const unsigned* __restrict__ maxk,
    const int* __restrict__ cnt, const float* __restrict__ W,
    const float* __restrict__ b, float* __restrict__ out) {
  int t = threadIdx.x;
  if (t >= NG * NCLS) return;
  int g = t / NCLS, k = t % NCLS;
  float accv = b[k];
  float inv = 1.f / fmaxf((float)cnt[g], 1.f);
  for (int j = 0; j < DD2; j++) accv += (sums[g * DD2 + j] * inv) * W[j * NCLS + k];
  for (int j = 0; j < DD2; j++) {
    float mx = funkey(maxk[g * DD2 + j]);
    if (mx < -3e38f) mx = 0.f;
    accv += mx * W[(DD2 + j) * NCLS + k];
  }
  out[g * NCLS + k] = accv;
}

// ---------------- launch ----------------
extern "C" void kernel_launch(void* const* d_in, const int* in_sizes, int n_in,
                              void* d_out, int out_size, void* d_ws, size_t ws_size,
                              hipStream_t stream) {
  (void)in_sizes; (void)n_in; (void)out_size; (void)ws_size;
  const float* x       = (const float*)d_in[0];
  const float* eattr   = (const float*)d_in[1];
  const int*   ei      = (const int*)d_in[2];
  const int*   batch   = (const int*)d_in[3];
  const float* c1_Wl   = (const float*)d_in[4];
  const float* c1_bl   = (const float*)d_in[5];
  const float* c1_Wr   = (const float*)d_in[6];
  const float* c1_br   = (const float*)d_in[7];
  const float* c1_We   = (const float*)d_in[8];
  const float* c1_att  = (const float*)d_in[9];
  const float* c1_bias = (const float*)d_in[10];
  const float* bn1_g   = (const float*)d_in[11];
  const float* bn1_b   = (const float*)d_in[12];
  const float* bn1_m   = (const float*)d_in[13];
  const float* bn1_v   = (const float*)d_in[14];
  const float* sp1_W   = (const float*)d_in[15];
  const float* sp1_b   = (const float*)d_in[16];
  const float* c2_Wl   = (const float*)d_in[17];
  const float* c2_bl   = (const float*)d_in[18];
  const float* c2_Wr   = (const float*)d_in[19];
  const float* c2_br   = (const float*)d_in[20];
  const float* c2_We   = (const float*)d_in[21];
  const float* c2_att  = (const float*)d_in[22];
  const float* c2_bias = (const float*)d_in[23];
  const float* bn2_g   = (const float*)d_in[24];
  const float* bn2_b   = (const float*)d_in[25];
  const float* bn2_m   = (const float*)d_in[26];
  const float* bn2_v   = (const float*)d_in[27];
  const float* sp2_W   = (const float*)d_in[28];
  const float* sp2_b   = (const float*)d_in[29];
  const float* cls_W   = (const float*)d_in[30];
  const float* cls_b   = (const float*)d_in[31];

  float* w     = (float*)d_ws;
  float* A     = w;                                 // N*64: xl (both layers)
  float* B     = A + (size_t)NN * DD1;              // N*64: xr
  float* Cb    = B + (size_t)NN * DD1;              // N*64: xp (skip)
  float* H1    = Cb + (size_t)NN * DD1;             // N*64: h1; then h2 (N*32)
  float* EXP   = H1 + (size_t)NN * DD1;             // E*2: exp scores (CSR order)
  int* srcs    = (int*)(EXP + (size_t)NE * HH1);    // E
  int* posm    = srcs + NE;                         // E
  int* rowptr  = posm + NE;                         // N
  int* deg     = rowptr + NN;                       // N
  int* fillc   = deg + NN;                          // N
  int* bsum    = fillc + NN;                        // NB_SCAN
  int* boff    = bsum + NB_SCAN;                    // NB_SCAN
  float* PS    = (float*)(boff + NB_SCAN);          // NG*32
  unsigned* PM = (unsigned*)(PS + NG * DD2);        // NG*32
  int* PC      = (int*)(PM + NG * DD2);             // NG

  int tgrid = (NN + 31) / 32;
  int egrid = (NE + 255) / 256;

  // ---- CSR build (shared by both layers) ----
  hipMemsetAsync(deg, 0, (size_t)NN * sizeof(int), stream);
  hipMemsetAsync(fillc, 0, (size_t)NN * sizeof(int), stream);
  hist_k<<<egrid, 256, 0, stream>>>(ei, deg);
  scan_bsum_k<<<NB_SCAN, 256, 0, stream>>>(deg, bsum, NN);
  scan_boff_k<<<1, 64, 0, stream>>>(bsum, boff, NB_SCAN);
  scan_rowptr_k<<<NB_SCAN, 256, 0, stream>>>(deg, boff, rowptr, NN);
  fill_k<<<egrid, 256, 0, stream>>>(ei, rowptr, fillc, srcs, posm);

  // ---- layer 1 ----
  transform_k<FIN, DD1><<<tgrid, 256, 0, stream>>>(x, c1_Wl, c1_bl, A, NN);
  transform_k<FIN, DD1><<<tgrid, 256, 0, stream>>>(x, c1_Wr, c1_br, B, NN);
  transform_k<FIN, DD1><<<tgrid, 256, 0, stream>>>(x, sp1_W, sp1_b, Cb, NN);
  score_k<DD1, HH1><<<egrid, 256, 0, stream>>>(ei, eattr, A, B, c1_We, c1_att, posm, EXP);
  gather_k<DD1, HH1><<<(NN * DD1 + 255) / 256, 256, 0, stream>>>(
      rowptr, deg, srcs, EXP, A, c1_bias, bn1_g, bn1_b, bn1_m, bn1_v, Cb, H1);

  // ---- layer 2 ----
  transform_k<DD1, DD2><<<tgrid, 256, 0, stream>>>(H1, c2_Wl, c2_bl, A, NN);
  transform_k<DD1, DD2><<<tgrid, 256, 0, stream>>>(H1, c2_Wr, c2_br, B, NN);
  transform_k<DD1, DD2><<<tgrid, 256, 0, stream>>>(H1, sp2_W, sp2_b, Cb, NN);
  score_k<DD2, 1><<<egrid, 256, 0, stream>>>(ei, eattr, A, B, c2_We, c2_att, posm, EXP);
  gather_k<DD2, 1><<<(NN * DD2 + 255) / 256, 256, 0, stream>>>(
      rowptr, deg, srcs, EXP, A, c2_bias, bn2_g, bn2_b, bn2_m, bn2_v, Cb, H1);

  // ---- pooling + classifier ----
  pool_init_k<<<(NG * DD2 + 255) / 256, 256, 0, stream>>>(PS, PM, PC);
  pool_accum_k<<<(NN + 255) / 256, 256, 0, stream>>>(H1, batch, PS, PM, PC);
  classify_k<<<1, 128, 0, stream>>>(PS, PM, PC, cls_W, cls_b, (float*)d_out);
}

// Round 8
// 1028.335 us; speedup vs baseline: 8.9633x; 1.1225x over previous
//
#include <hip/hip_runtime.h>
#include <math.h>

#define NN 50000
#define NE 1600000
#define FIN 128
#define EDIM 16
#define DD1 64
#define HH1 2
#define DD2 32
#define NG 64
#define NCLS 2
#define SCAN_CHUNK 512
#define NB_SCAN ((NN + SCAN_CHUNK - 1) / SCAN_CHUNK)   // 98

// ---------------- node transform: out[n, OUT] = X[n, IN] @ W + b ----------------
template<int IN, int OUT>
__global__ __launch_bounds__(256) void transform_k(const float* __restrict__ X,
    const float* __restrict__ W, const float* __restrict__ b,
    float* __restrict__ out, int n) {
  constexpr int NPB = 32;            // nodes per block
  constexpr int TPN = 256 / NPB;     // 8 threads per node
  constexpr int CPT = OUT / TPN;     // cols per thread
  __shared__ float sW[IN * OUT];
  __shared__ float sX[NPB * IN];
  int t = threadIdx.x;
  int nodeBase = blockIdx.x * NPB;
  for (int i = t; i < IN * OUT; i += 256) sW[i] = W[i];
  constexpr int XE = NPB * IN / 4;
  const float4* X4 = (const float4*)X;
  float4* sX4 = (float4*)sX;
  for (int i = t; i < XE; i += 256) {
    int node = nodeBase + i / (IN / 4);
    sX4[i] = (node < n) ? X4[(size_t)node * (IN / 4) + i % (IN / 4)]
                        : make_float4(0.f, 0.f, 0.f, 0.f);
  }
  __syncthreads();
  int ln = t / TPN;
  int cb = (t % TPN) * CPT;
  int node = nodeBase + ln;
  float acc[CPT];
#pragma unroll
  for (int j = 0; j < CPT; j++) acc[j] = b[cb + j];
  const float* xs = &sX[ln * IN];
  for (int k = 0; k < IN; k++) {
    float xv = xs[k];
#pragma unroll
    for (int j = 0; j < CPT; j++) acc[j] += xv * sW[k * OUT + cb + j];
  }
  if (node < n) {
#pragma unroll
    for (int j = 0; j < CPT; j++) out[(size_t)node * OUT + cb + j] = acc[j];
  }
}

// ---------------- CSR build ----------------
__global__ __launch_bounds__(256) void hist_k(const int* __restrict__ ei, int* __restrict__ deg) {
  int e = blockIdx.x * 256 + threadIdx.x;
  if (e >= NE) return;
  atomicAdd(&deg[ei[NE + e]], 1);
}

__global__ __launch_bounds__(256) void scan_bsum_k(const int* __restrict__ deg,
                                                   int* __restrict__ bsum, int n) {
  __shared__ int s[256];
  int b = blockIdx.x, t = threadIdx.x;
  int i0 = b * SCAN_CHUNK + 2 * t, i1 = i0 + 1;
  int v = ((i0 < n) ? deg[i0] : 0) + ((i1 < n) ? deg[i1] : 0);
  s[t] = v;
  __syncthreads();
  for (int off = 128; off; off >>= 1) {
    if (t < off) s[t] += s[t + off];
    __syncthreads();
  }
  if (t == 0) bsum[b] = s[0];
}

__global__ void scan_boff_k(const int* __restrict__ bsum, int* __restrict__ boff, int nb) {
  if (threadIdx.x == 0) {
    int run = 0;
    for (int i = 0; i < nb; i++) { int v = bsum[i]; boff[i] = run; run += v; }
  }
}

__global__ __launch_bounds__(256) void scan_rowptr_k(const int* __restrict__ deg,
    const int* __restrict__ boff, int* __restrict__ rowptr, int n) {
  __shared__ int s[256];
  int b = blockIdx.x, t = threadIdx.x;
  int i0 = b * SCAN_CHUNK + 2 * t, i1 = i0 + 1;
  int d0 = (i0 < n) ? deg[i0] : 0;
  int d1 = (i1 < n) ? deg[i1] : 0;
  s[t] = d0 + d1;
  __syncthreads();
  for (int off = 1; off < 256; off <<= 1) {
    int add = (t >= off) ? s[t - off] : 0;
    __syncthreads();
    s[t] += add;
    __syncthreads();
  }
  int excl = (t == 0) ? 0 : s[t - 1];
  int o = boff[b] + excl;
  if (i0 < n) rowptr[i0] = o;
  if (i1 < n) rowptr[i1] = o + d0;
}

__global__ __launch_bounds__(256) void fill_k(const int* __restrict__ ei,
    const int* __restrict__ rowptr, int* __restrict__ fillc,
    int* __restrict__ srcs_perm, int* __restrict__ dstv, int* __restrict__ eperm) {
  int e = blockIdx.x * 256 + threadIdx.x;
  if (e >= NE) return;
  int src = ei[e], dst = ei[NE + e];
  int pos = rowptr[dst] + atomicAdd(&fillc[dst], 1);
  srcs_perm[pos] = src;
  dstv[pos] = dst;
  eperm[pos] = e;
}

// ---------------- edge score pass (CSR order): ex_perm[p*H+h] = exp(score) ----------------
template<int D, int H>
__global__ __launch_bounds__(256) void score_csr_k(
    const int* __restrict__ srcs_perm, const int* __restrict__ dstv,
    const int* __restrict__ eperm, const float* __restrict__ eattr,
    const float* __restrict__ xl, const float* __restrict__ xr,
    const float* __restrict__ We, const float* __restrict__ att,
    float* __restrict__ ex_perm) {
  constexpr int C = D / H;
  __shared__ float sWe[EDIM * D];
  __shared__ float sAtt[D];
  int t = threadIdx.x;
  for (int i = t; i < EDIM * D; i += 256) sWe[i] = We[i];
  for (int i = t; i < D; i += 256) sAtt[i] = att[i];
  __syncthreads();
  int p = blockIdx.x * 256 + t;
  if (p >= NE) return;
  int src = srcs_perm[p], dst = dstv[p], e = eperm[p];
  float ea[EDIM];
  const float4* ea4 = (const float4*)(eattr + (size_t)e * EDIM);
#pragma unroll
  for (int q = 0; q < EDIM / 4; q++) {
    float4 v = ea4[q];
    ea[4 * q] = v.x; ea[4 * q + 1] = v.y; ea[4 * q + 2] = v.z; ea[4 * q + 3] = v.w;
  }
  const float4* xls = (const float4*)(xl + (size_t)src * D);
  const float4* xrd = (const float4*)(xr + (size_t)dst * D);
  float sc[H];
#pragma unroll
  for (int h = 0; h < H; h++) sc[h] = 0.f;
#pragma unroll
  for (int q = 0; q < D / 4; q++) {
    float4 a = xls[q], r = xrd[q];
    float av[4] = {a.x, a.y, a.z, a.w};
    float rv[4] = {r.x, r.y, r.z, r.w};
#pragma unroll
    for (int j = 0; j < 4; j++) {
      int hc = 4 * q + j;
      float ef = 0.f;
#pragma unroll
      for (int k = 0; k < EDIM; k++) ef += ea[k] * sWe[k * D + hc];
      float m = av[j] + rv[j] + ef;
      m = m > 0.f ? m : 0.2f * m;
      sc[hc / C] += m * sAtt[hc];
    }
  }
  if (H == 2) {
    float2 ex2 = make_float2(expf(sc[0]), expf(sc[H - 1]));
    *(float2*)&ex_perm[(size_t)p * 2] = ex2;
  } else {
#pragma unroll
    for (int h = 0; h < H; h++) ex_perm[(size_t)p * H + h] = expf(sc[h]);
  }
}

// ---------------- gather: per-dst softmax + weighted sum + BN/skip/ELU ----------------
template<int D, int H>
__global__ __launch_bounds__(256) void gather_k(
    const int* __restrict__ rowptr, const int* __restrict__ deg,
    const int* __restrict__ srcs_perm, const float* __restrict__ ex_perm,
    const float* __restrict__ xl, const float* __restrict__ bias,
    const float* __restrict__ gamma, const float* __restrict__ beta,
    const float* __restrict__ mean, const float* __restrict__ var,
    const float* __restrict__ xp, float* __restrict__ hout) {
  constexpr int C = D / H;
  int gid = (blockIdx.x * 256 + threadIdx.x) / D;   // dst node
  int lane = threadIdx.x % D;                        // channel
  if (gid >= NN) return;
  int start = rowptr[gid];
  int len = deg[gid];
  // phase 1: softmax denominator per head
  float den[H];
#pragma unroll
  for (int h = 0; h < H; h++) den[h] = 0.f;
  for (int j = lane; j < len; j += D) {
#pragma unroll
    for (int h = 0; h < H; h++) den[h] += ex_perm[(size_t)(start + j) * H + h];
  }
#pragma unroll
  for (int off = D / 2; off; off >>= 1) {
#pragma unroll
    for (int h = 0; h < H; h++) den[h] += __shfl_xor(den[h], off, D);
  }
  float inv[H];
#pragma unroll
  for (int h = 0; h < H; h++) inv[h] = 1.f / (den[h] + 1e-16f);
  // phase 2: weighted gather, channel per lane
  int h = lane / C;
  float myinv = inv[h];
  float acc = 0.f;
  for (int j = 0; j < len; j++) {
    int src = srcs_perm[start + j];
    float exv = ex_perm[(size_t)(start + j) * H + h];
    acc += xl[(size_t)src * D + lane] * (exv * myinv);
  }
  // epilogue: bias + BN + skip + ELU
  float v = acc + bias[lane];
  v = (v - mean[lane]) * gamma[lane] * rsqrtf(var[lane] + 1e-5f) + beta[lane];
  v += xp[(size_t)gid * D + lane];
  hout[(size_t)gid * D + lane] = v > 0.f ? v : expm1f(v);
}

// ---------------- pooling ----------------
__device__ inline unsigned fkey(float f) {
  unsigned u = __float_as_uint(f);
  return (u & 0x80000000u) ? ~u : (u | 0x80000000u);
}
__device__ inline float funkey(unsigned k) {
  unsigned u = (k & 0x80000000u) ? (k & 0x7FFFFFFFu) : ~k;
  return __uint_as_float(u);
}

__global__ __launch_bounds__(256) void pool_init_k(float* sums, unsigned* maxk, int* cnt) {
  int t = blockIdx.x * 256 + threadIdx.x;
  if (t < NG * DD2) { sums[t] = 0.f; maxk[t] = fkey(-INFINITY); }
  if (t < NG) cnt[t] = 0;
}

// hierarchical: LDS partials per (graph-in-span, channel), then few global atomics.
#define PSPAN 16
__global__ __launch_bounds__(256) void pool_accum_k(const float* __restrict__ h2,
    const int* __restrict__ batch, float* sums, unsigned* maxk, int* cnt) {
  __shared__ float ls[PSPAN][DD2];
  __shared__ unsigned lm[PSPAN][DD2];
  __shared__ int lc[PSPAN];
  int base = blockIdx.x * 256;
  int t = threadIdx.x;
  int c = t % DD2;       // channel
  int nsub = t / DD2;    // 0..7
  int lastNode = min(base + 256, NN) - 1;
  int gmin = batch[base];
  int gmax = batch[lastNode];
  for (int gbase = gmin; gbase <= gmax; gbase += PSPAN) {
    int span = min(PSPAN, gmax - gbase + 1);
    for (int i = t; i < span * DD2; i += 256) {
      ls[i / DD2][i % DD2] = 0.f;
      lm[i / DD2][i % DD2] = fkey(-INFINITY);
    }
    if (t < span) lc[t] = 0;
    __syncthreads();
    for (int nnode = base + nsub; nnode < base + 256 && nnode < NN; nnode += 8) {
      int g = batch[nnode] - gbase;
      if (g >= 0 && g < span) {
        float v = h2[(size_t)nnode * DD2 + c];
        atomicAdd(&ls[g][c], v);
        atomicMax(&lm[g][c], fkey(v));
        if (c == 0) atomicAdd(&lc[g], 1);
      }
    }
    __syncthreads();
    for (int i = t; i < span * DD2; i += 256) {
      int g = gbase + i / DD2;
      atomicAdd(&sums[g * DD2 + i % DD2], ls[i / DD2][i % DD2]);
      atomicMax(&maxk[g * DD2 + i % DD2], lm[i / DD2][i % DD2]);
    }
    if (t < span) atomicAdd(&cnt[gbase + t], lc[t]);
    __syncthreads();
  }
}

__global__ void classify_k(const float* __restrict__ sums, const unsigned* __restrict__ maxk,
    const int* __restrict__ cnt, const float* __restrict__ W,
    const float* __restrict__ b, float* __restrict__ out) {
  int t = threadIdx.x;
  if (t >= NG * NCLS) return;
  int g = t / NCLS, k = t % NCLS;
  float accv = b[k];
  float inv = 1.f / fmaxf((float)cnt[g], 1.f);
  for (int j = 0; j < DD2; j++) accv += (sums[g * DD2 + j] * inv) * W[j * NCLS + k];
  for (int j = 0; j < DD2; j++) {
    float mx = funkey(maxk[g * DD2 + j]);
    if (mx < -3e38f) mx = 0.f;
    accv += mx * W[(DD2 + j) * NCLS + k];
  }
  out[g * NCLS + k] = accv;
}

// ---------------- launch ----------------
extern "C" void kernel_launch(void* const* d_in, const int* in_sizes, int n_in,
                              void* d_out, int out_size, void* d_ws, size_t ws_size,
                              hipStream_t stream) {
  (void)in_sizes; (void)n_in; (void)out_size; (void)ws_size;
  const float* x       = (const float*)d_in[0];
  const float* eattr   = (const float*)d_in[1];
  const int*   ei      = (const int*)d_in[2];
  const int*   batch   = (const int*)d_in[3];
  const float* c1_Wl   = (const float*)d_in[4];
  const float* c1_bl   = (const float*)d_in[5];
  const float* c1_Wr   = (const float*)d_in[6];
  const float* c1_br   = (const float*)d_in[7];
  const float* c1_We   = (const float*)d_in[8];
  const float* c1_att  = (const float*)d_in[9];
  const float* c1_bias = (const float*)d_in[10];
  const float* bn1_g   = (const float*)d_in[11];
  const float* bn1_b   = (const float*)d_in[12];
  const float* bn1_m   = (const float*)d_in[13];
  const float* bn1_v   = (const float*)d_in[14];
  const float* sp1_W   = (const float*)d_in[15];
  const float* sp1_b   = (const float*)d_in[16];
  const float* c2_Wl   = (const float*)d_in[17];
  const float* c2_bl   = (const float*)d_in[18];
  const float* c2_Wr   = (const float*)d_in[19];
  const float* c2_br   = (const float*)d_in[20];
  const float* c2_We   = (const float*)d_in[21];
  const float* c2_att  = (const float*)d_in[22];
  const float* c2_bias = (const float*)d_in[23];
  const float* bn2_g   = (const float*)d_in[24];
  const float* bn2_b   = (const float*)d_in[25];
  const float* bn2_m   = (const float*)d_in[26];
  const float* bn2_v   = (const float*)d_in[27];
  const float* sp2_W   = (const float*)d_in[28];
  const float* sp2_b   = (const float*)d_in[29];
  const float* cls_W   = (const float*)d_in[30];
  const float* cls_b   = (const float*)d_in[31];

  float* w     = (float*)d_ws;
  float* A     = w;                                 // N*64: xl (both layers)
  float* B     = A + (size_t)NN * DD1;              // N*64: xr
  float* Cb    = B + (size_t)NN * DD1;              // N*64: xp (skip)
  float* H1    = Cb + (size_t)NN * DD1;             // N*64: h1; then h2 (N*32)
  float* EXP   = H1 + (size_t)NN * DD1;             // E*2: exp scores (CSR order)
  int* srcs    = (int*)(EXP + (size_t)NE * HH1);    // E
  int* dstv    = srcs + NE;                         // E
  int* eperm   = dstv + NE;                         // E
  int* rowptr  = eperm + NE;                        // N
  int* deg     = rowptr + NN;                       // N
  int* fillc   = deg + NN;                          // N
  int* bsum    = fillc + NN;                        // NB_SCAN
  int* boff    = bsum + NB_SCAN;                    // NB_SCAN
  float* PS    = (float*)(boff + NB_SCAN);          // NG*32
  unsigned* PM = (unsigned*)(PS + NG * DD2);        // NG*32
  int* PC      = (int*)(PM + NG * DD2);             // NG

  int tgrid = (NN + 31) / 32;
  int egrid = (NE + 255) / 256;

  // ---- CSR build (shared by both layers) ----
  hipMemsetAsync(deg, 0, (size_t)NN * sizeof(int), stream);
  hipMemsetAsync(fillc, 0, (size_t)NN * sizeof(int), stream);
  hist_k<<<egrid, 256, 0, stream>>>(ei, deg);
  scan_bsum_k<<<NB_SCAN, 256, 0, stream>>>(deg, bsum, NN);
  scan_boff_k<<<1, 64, 0, stream>>>(bsum, boff, NB_SCAN);
  scan_rowptr_k<<<NB_SCAN, 256, 0, stream>>>(deg, boff, rowptr, NN);
  fill_k<<<egrid, 256, 0, stream>>>(ei, rowptr, fillc, srcs, dstv, eperm);

  // ---- layer 1 ----
  transform_k<FIN, DD1><<<tgrid, 256, 0, stream>>>(x, c1_Wl, c1_bl, A, NN);
  transform_k<FIN, DD1><<<tgrid, 256, 0, stream>>>(x, c1_Wr, c1_br, B, NN);
  transform_k<FIN, DD1><<<tgrid, 256, 0, stream>>>(x, sp1_W, sp1_b, Cb, NN);
  score_csr_k<DD1, HH1><<<egrid, 256, 0, stream>>>(srcs, dstv, eperm, eattr, A, B, c1_We, c1_att, EXP);
  gather_k<DD1, HH1><<<(NN * DD1 + 255) / 256, 256, 0, stream>>>(
      rowptr, deg, srcs, EXP, A, c1_bias, bn1_g, bn1_b, bn1_m, bn1_v, Cb, H1);

  // ---- layer 2 ----
  transform_k<DD1, DD2><<<tgrid, 256, 0, stream>>>(H1, c2_Wl, c2_bl, A, NN);
  transform_k<DD1, DD2><<<tgrid, 256, 0, stream>>>(H1, c2_Wr, c2_br, B, NN);
  transform_k<DD1, DD2><<<tgrid, 256, 0, stream>>>(H1, sp2_W, sp2_b, Cb, NN);
  score_csr_k<DD2, 1><<<egrid, 256, 0, stream>>>(srcs, dstv, eperm, eattr, A, B, c2_We, c2_att, EXP);
  gather_k<DD2, 1><<<(NN * DD2 + 255) / 256, 256, 0, stream>>>(
      rowptr, deg, srcs, EXP, A, c2_bias, bn2_g, bn2_b, bn2_m, bn2_v, Cb, H1);

  // ---- pooling + classifier ----
  pool_init_k<<<(NG * DD2 + 255) / 256, 256, 0, stream>>>(PS, PM, PC);
  pool_accum_k<<<(NN + 255) / 256, 256, 0, stream>>>(H1, batch, PS, PM, PC);
  classify_k<<<1, 128, 0, stream>>>(PS, PM, PC, cls_W, cls_b, (float*)d_out);
}